// Round 3
// baseline (20.896 us; speedup 1.0000x reference)
//
#include <hip/hip_runtime.h>
#include <math.h>

#define NN 256
#define PP 32640        // N*(N-1)/2
#define HH 64
#define BB 32
#define NF4 (PP / 4)    // 8160 float4 per row

// Single fused kernel: one block per batch element, 1024 threads.
//
// Algebraic collapse (verified R1/R2, absmax 0.0): the GCN graph is the
// complete digraph + self-loops => norm = 1/256 everywhere and every conv
// output is node-independent. The whole net reduces to:
//   f0 = sum(deg)/255, f1 = #(deg==0), f2 = 2            (deg over accepted pairs)
//   g1 = relu((f @ W1)/256 + b1)                          (3 -> 64)
//   g2 = relu(g1 @ W2 + b2); g3 = relu(g2 @ W3 + b3)      (64 -> 64)
//   hm = relu([g3,g3,e0,e1,1] @ We1 + be1)                (131 -> 64)
//   out = sigmoid(hm @ We2 + be2)  (both directed edges of `cur` identical)
//
// Phase 1 (all 1024 threads): coalesced float4 scan of dec+ind, LDS degree
// histogram + one-hot index; concurrently other waves stage W2/W3/We1 into
// LDS (coalesced float4, pre-summing We1's two h-blocks).
// Phase 2 (wave 0): tiny matvec chain from LDS weights.
__global__ __launch_bounds__(1024) void gnn_fused(
    const float* __restrict__ x,
    const float* __restrict__ W1, const float* __restrict__ b1,
    const float* __restrict__ W2, const float* __restrict__ b2,
    const float* __restrict__ W3, const float* __restrict__ b3,
    const float* __restrict__ We1, const float* __restrict__ be1,
    const float* __restrict__ We2, const float* __restrict__ be2,
    float* __restrict__ out)
{
    const int b   = blockIdx.x;
    const int tid = threadIdx.x;

    __shared__ int   deg[NN];
    __shared__ int   s_cur, s_sum, s_zc;
    __shared__ float W2s[HH * HH];    // 16 KB
    __shared__ float W3s[HH * HH];    // 16 KB
    __shared__ float Wsum[HH * HH];   // 16 KB: We1[k] + We1[64+k] pre-summed
    __shared__ float Erow[3 * HH];    // We1 rows 128..130
    __shared__ float g[HH];

    if (tid < NN) deg[tid] = 0;
    if (tid == 0) { s_cur = 0; s_sum = 0; s_zc = 0; }
    __syncthreads();

    const float*  decp = x + (size_t)b * (2 * PP);
    const float4* dec4 = (const float4*)decp;
    const float4* ind4 = (const float4*)(decp + PP);

    // ---- scan: 8 coalesced float4 iterations per thread ----
    for (int q = tid; q < NF4; q += 1024) {
        float4 d  = dec4[q];
        float4 iv = ind4[q];
        const int p0 = q * 4;

        // invert triu_indices once per float4: O(i) = i*(511-i)/2
        int i = (int)((511.0f - sqrtf(261121.0f - 8.0f * (float)p0)) * 0.5f);
        while (i * (511 - i) / 2 > p0) --i;
        while ((i + 1) * (510 - i) / 2 <= p0) ++i;
        int rowStart = i * (511 - i) / 2;

        float dv[4]  = {d.x, d.y, d.z, d.w};
        float ivv[4] = {iv.x, iv.y, iv.z, iv.w};
        #pragma unroll
        for (int u = 0; u < 4; ++u) {
            const int p = p0 + u;
            while (p - rowStart >= 255 - i) { ++i; rowStart = i * (511 - i) / 2; }
            if (ivv[u] > 0.5f) s_cur = p;          // one-hot: single writer
            if (dv[u] == 1.0f) {
                const int j = i + 1 + (p - rowStart);
                atomicAdd(&deg[i], 1);
                atomicAdd(&deg[j], 1);
            }
        }
    }

    // ---- stage weights into LDS (coalesced float4; overlaps scan across waves) ----
    {
        const float4* W2g  = (const float4*)W2;
        const float4* W3g  = (const float4*)W3;
        const float4* We1g = (const float4*)We1;
        if (tid < 1024) {                 // 4096 floats each
            float4 v2 = W2g[tid];
            float4 v3 = W3g[tid];
            ((float4*)W2s)[tid] = v2;
            ((float4*)W3s)[tid] = v3;
            float4 a = We1g[tid];         // rows 0..63
            float4 c = We1g[1024 + tid];  // rows 64..127
            float4 sv; sv.x = a.x + c.x; sv.y = a.y + c.y; sv.z = a.z + c.z; sv.w = a.w + c.w;
            ((float4*)Wsum)[tid] = sv;
        }
        if (tid < 48) ((float4*)Erow)[tid] = We1g[2048 + tid];  // rows 128..130
    }
    __syncthreads();

    // ---- reduce histogram ----
    if (tid < NN) {
        const int dv = deg[tid];
        atomicAdd(&s_sum, dv);
        if (dv == 0) atomicAdd(&s_zc, 1);
    }
    __syncthreads();

    // ---- collapsed network, wave 0 only ----
    if (tid < HH) {
        const float f0 = (float)s_sum * (1.0f / 255.0f);
        const float f1 = (float)s_zc;
        const float f2 = 2.0f;
        float s = f0 * W1[0 * HH + tid] + f1 * W1[1 * HH + tid] + f2 * W1[2 * HH + tid];
        g[tid] = fmaxf(s * (1.0f / 256.0f) + b1[tid], 0.0f);
    }
    __syncthreads();

    if (tid < HH) {
        float s = b2[tid];
        #pragma unroll 8
        for (int k = 0; k < HH; ++k) s += g[k] * W2s[k * HH + tid];
        const float v = fmaxf(s, 0.0f);
        __builtin_amdgcn_wave_barrier();
        g[tid] = v;
    }
    __syncthreads();

    if (tid < HH) {
        float s = b3[tid];
        #pragma unroll 8
        for (int k = 0; k < HH; ++k) s += g[k] * W3s[k * HH + tid];
        const float v = fmaxf(s, 0.0f);
        __builtin_amdgcn_wave_barrier();
        g[tid] = v;
    }
    __syncthreads();

    if (tid < HH) {
        const int   cur  = s_cur;
        const float dcur = decp[cur];                  // broadcast load
        const float e0 = (dcur == 1.0f) ? 1.0f : 0.0f;
        const float e1 = (dcur != 0.5f) ? 1.0f : 0.0f;

        float s = be1[tid];
        #pragma unroll 8
        for (int k = 0; k < HH; ++k) s += g[k] * Wsum[k * HH + tid];
        s += e0 * Erow[0 * HH + tid] + e1 * Erow[1 * HH + tid] + Erow[2 * HH + tid];
        const float hm = fmaxf(s, 0.0f);

        float contrib = hm * We2[tid];
        #pragma unroll
        for (int off = 32; off > 0; off >>= 1)
            contrib += __shfl_down(contrib, off);

        if (tid == 0) {
            const float logit = contrib + be2[0];
            const float sig = 1.0f / (1.0f + expf(-logit));
            out[b * 2 + 0] = sig;
            out[b * 2 + 1] = sig;
        }
    }
}

extern "C" void kernel_launch(void* const* d_in, const int* in_sizes, int n_in,
                              void* d_out, int out_size, void* d_ws, size_t ws_size,
                              hipStream_t stream) {
    const float* x   = (const float*)d_in[0];
    const float* W1  = (const float*)d_in[1];
    const float* b1  = (const float*)d_in[2];
    const float* W2  = (const float*)d_in[3];
    const float* b2  = (const float*)d_in[4];
    const float* W3  = (const float*)d_in[5];
    const float* b3  = (const float*)d_in[6];
    const float* We1 = (const float*)d_in[7];
    const float* be1 = (const float*)d_in[8];
    const float* We2 = (const float*)d_in[9];
    const float* be2 = (const float*)d_in[10];
    float* out = (float*)d_out;

    gnn_fused<<<BB, 1024, 0, stream>>>(x, W1, b1, W2, b2, W3, b3,
                                       We1, be1, We2, be2, out);
}

// Round 4
// 13.824 us; speedup vs baseline: 1.5116x; 1.5116x over previous
//
#include <hip/hip_runtime.h>
#include <math.h>

#define NN 256
#define PP 32640            // N*(N-1)/2
#define HH 64
#define BB 32
#define SPLIT 32            // scan blocks per batch
#define NF4 (PP / 4)        // 8160 float4 per row
#define F4_PER (NF4 / SPLIT) // 255 float4 per chunk

// Algebraic collapse (verified absmax 0.0 in R1-R3): complete digraph + self
// loops => norm = 1/256 and conv outputs are node-independent. Additionally:
//   sum(deg) = 2 * count(dec==1)          (no histogram needed)
//   #(deg==0) = 256 - popcount(OR of per-pair touched masks)
// so the scan reduces to {count, 256-bit mask, one-hot index} per chunk.

// ---------------------------------------------------------------------------
// Kernel 1: per-(batch,chunk) scan, 1024 blocks x 256 threads, NO atomics.
// Each thread handles one float4 of dec + ind. Outputs per block: 8 mask
// words + 1 count (plain stores, poison-safe).
// ---------------------------------------------------------------------------
__global__ __launch_bounds__(256) void gnn_scan(
    const float* __restrict__ x,
    unsigned int* __restrict__ ws_mask,  // [BB*SPLIT][8]
    int* __restrict__ ws_cnt,            // [BB*SPLIT]
    int* __restrict__ ws_cur)            // [BB]
{
    const int blk   = blockIdx.x;
    const int b     = blk >> 5;          // / SPLIT
    const int chunk = blk & (SPLIT - 1);
    const int tid   = threadIdx.x;
    const int lane  = tid & 63;
    const int w     = tid >> 6;

    __shared__ unsigned char touched[NN];
    __shared__ int wcnt[4];
    touched[tid] = 0;
    __syncthreads();

    const float*  decp = x + (size_t)b * (2 * PP);
    const float4* dec4 = (const float4*)decp;
    const float4* ind4 = (const float4*)(decp + PP);

    int cnt = 0;
    if (tid < F4_PER) {
        const int q  = chunk * F4_PER + tid;
        float4 d  = dec4[q];
        float4 iv = ind4[q];
        const int p0 = q * 4;

        // invert triu_indices once: O(i) = i*(511-i)/2 (exact in fp32 here)
        int i = (int)((511.0f - sqrtf(261121.0f - 8.0f * (float)p0)) * 0.5f);
        while (i * (511 - i) / 2 > p0) --i;
        while ((i + 1) * (510 - i) / 2 <= p0) ++i;
        int rowStart = i * (511 - i) / 2;

        float dv[4]  = {d.x, d.y, d.z, d.w};
        float ivv[4] = {iv.x, iv.y, iv.z, iv.w};
        #pragma unroll
        for (int u = 0; u < 4; ++u) {
            const int p = p0 + u;
            while (p - rowStart >= 255 - i) { ++i; rowStart = i * (511 - i) / 2; }
            if (ivv[u] > 0.5f) ws_cur[b] = p;        // one-hot: single writer
            if (dv[u] == 1.0f) {
                const int j = i + 1 + (p - rowStart);
                touched[i] = 1;                       // racy-identical: benign
                touched[j] = 1;
                ++cnt;
            }
        }
    }
    __syncthreads();

    // node t touched? -> one ballot per wave -> 2 mask words
    const bool bit = touched[tid] != 0;
    unsigned long long m = __ballot(bit);
    if (lane == 0) {
        ws_mask[blk * 8 + w * 2 + 0] = (unsigned int)m;
        ws_mask[blk * 8 + w * 2 + 1] = (unsigned int)(m >> 32);
    }
    #pragma unroll
    for (int off = 32; off > 0; off >>= 1) cnt += __shfl_down(cnt, off);
    if (lane == 0) wcnt[w] = cnt;
    __syncthreads();
    if (tid == 0) ws_cnt[blk] = wcnt[0] + wcnt[1] + wcnt[2] + wcnt[3];
}

// ---------------------------------------------------------------------------
// Kernel 2: one block per batch, 256 threads. OR-reduce masks + sum counts,
// then the matvec chain with k split across the 4 waves (16 k's each).
// ---------------------------------------------------------------------------
__global__ __launch_bounds__(256) void gnn_epilogue(
    const float* __restrict__ x,
    const float* __restrict__ W1, const float* __restrict__ b1,
    const float* __restrict__ W2, const float* __restrict__ b2,
    const float* __restrict__ W3, const float* __restrict__ b3,
    const float* __restrict__ We1, const float* __restrict__ be1,
    const float* __restrict__ We2, const float* __restrict__ be2,
    const unsigned int* __restrict__ ws_mask,
    const int* __restrict__ ws_cnt,
    const int* __restrict__ ws_cur,
    float* __restrict__ out)
{
    const int b    = blockIdx.x;
    const int tid  = threadIdx.x;
    const int lane = tid & 63;
    const int w    = tid >> 6;

    __shared__ float gS[HH];
    __shared__ float p[4][HH];
    __shared__ unsigned int mw[SPLIT * 8];
    __shared__ int s_pop, s_cnt;

    if (tid == 0) s_pop = 0;
    mw[tid] = ws_mask[b * (SPLIT * 8) + tid];              // coalesced 1 KB
    const int cv   = (tid < SPLIT) ? ws_cnt[b * SPLIT + tid] : 0;
    const int cur  = ws_cur[b];
    const float dcur = x[(size_t)b * (2 * PP) + cur];      // broadcast load
    __syncthreads();

    if (tid < 8) {
        unsigned int o = 0;
        #pragma unroll
        for (int c = 0; c < SPLIT; ++c) o |= mw[c * 8 + tid];
        atomicAdd(&s_pop, __popc(o));
    }
    if (w == 0) {
        int s = cv;
        #pragma unroll
        for (int off = 32; off > 0; off >>= 1) s += __shfl_down(s, off);
        if (lane == 0) s_cnt = s;
    }
    __syncthreads();

    const float f0 = (float)(2 * s_cnt) * (1.0f / 255.0f); // sum(deg)/255
    const float f1 = (float)(NN - s_pop);                  // #(deg==0)

    if (tid < HH) {
        float s = f0 * W1[tid] + f1 * W1[HH + tid] + 2.0f * W1[2 * HH + tid];
        gS[tid] = fmaxf(s * (1.0f / 256.0f) + b1[tid], 0.0f);
    }
    __syncthreads();

    // g2 = relu(g1 @ W2 + b2), k split over waves
    {
        float s = 0.0f;
        const float* Wp = W2 + (w * 16) * HH + lane;
        #pragma unroll
        for (int kk = 0; kk < 16; ++kk) s += gS[w * 16 + kk] * Wp[kk * HH];
        p[w][lane] = s;
    }
    __syncthreads();
    if (tid < HH)
        gS[tid] = fmaxf(p[0][tid] + p[1][tid] + p[2][tid] + p[3][tid] + b2[tid], 0.0f);
    __syncthreads();

    // g3 = relu(g2 @ W3 + b3)
    {
        float s = 0.0f;
        const float* Wp = W3 + (w * 16) * HH + lane;
        #pragma unroll
        for (int kk = 0; kk < 16; ++kk) s += gS[w * 16 + kk] * Wp[kk * HH];
        p[w][lane] = s;
    }
    __syncthreads();
    if (tid < HH)
        gS[tid] = fmaxf(p[0][tid] + p[1][tid] + p[2][tid] + p[3][tid] + b3[tid], 0.0f);
    __syncthreads();

    // hm = relu([g3,g3,e0,e1,1] @ We1 + be1)  (We1 h-rows pre-summed on the fly)
    {
        float s = 0.0f;
        const float* Wa = We1 + (w * 16) * HH + lane;
        const float* Wb = We1 + (64 + w * 16) * HH + lane;
        #pragma unroll
        for (int kk = 0; kk < 16; ++kk)
            s += gS[w * 16 + kk] * (Wa[kk * HH] + Wb[kk * HH]);
        p[w][lane] = s;
    }
    __syncthreads();
    if (tid < HH) {   // exactly wave 0
        const float e0 = (dcur == 1.0f) ? 1.0f : 0.0f;
        const float e1 = (dcur != 0.5f) ? 1.0f : 0.0f;
        float v = p[0][tid] + p[1][tid] + p[2][tid] + p[3][tid] + be1[tid]
                + e0 * We1[128 * HH + tid] + e1 * We1[129 * HH + tid]
                + We1[130 * HH + tid];
        v = fmaxf(v, 0.0f);

        float contrib = v * We2[tid];
        #pragma unroll
        for (int off = 32; off > 0; off >>= 1)
            contrib += __shfl_down(contrib, off);

        if (tid == 0) {
            const float sig = 1.0f / (1.0f + expf(-(contrib + be2[0])));
            out[b * 2 + 0] = sig;
            out[b * 2 + 1] = sig;
        }
    }
}

extern "C" void kernel_launch(void* const* d_in, const int* in_sizes, int n_in,
                              void* d_out, int out_size, void* d_ws, size_t ws_size,
                              hipStream_t stream) {
    const float* x   = (const float*)d_in[0];
    const float* W1  = (const float*)d_in[1];
    const float* b1  = (const float*)d_in[2];
    const float* W2  = (const float*)d_in[3];
    const float* b2  = (const float*)d_in[4];
    const float* W3  = (const float*)d_in[5];
    const float* b3  = (const float*)d_in[6];
    const float* We1 = (const float*)d_in[7];
    const float* be1 = (const float*)d_in[8];
    const float* We2 = (const float*)d_in[9];
    const float* be2 = (const float*)d_in[10];
    float* out = (float*)d_out;

    unsigned int* ws_mask = (unsigned int*)d_ws;                 // 32 KB
    int* ws_cnt = (int*)(ws_mask + (size_t)BB * SPLIT * 8);      // 4 KB
    int* ws_cur = ws_cnt + (size_t)BB * SPLIT;                   // 128 B

    gnn_scan<<<BB * SPLIT, 256, 0, stream>>>(x, ws_mask, ws_cnt, ws_cur);
    gnn_epilogue<<<BB, 256, 0, stream>>>(x, W1, b1, W2, b2, W3, b3,
                                         We1, be1, We2, be2,
                                         ws_mask, ws_cnt, ws_cur, out);
}